// Round 17
// baseline (263.296 us; speedup 1.0000x reference)
//
#include <hip/hip_runtime.h>
#include <math.h>

#define NG   2048
#define NN   48
#define FIN  64
#define HIDC 128
#define DEG  8
#define EPG  (NN*DEG)   // 384 edges per graph
#define NATT 8
#define KTOP 4
#define NTH  256
#define OUTW (KTOP*HIDC + NATT)  // 520

struct alignas(16) SM {
  float hA[NN*HIDC];        // 24KB
  float hB[NN*HIDC];        // 24KB message buffer (layers only)
  float alpha[EPG];         // per-edge alpha; reused as attn logits (48*8)
  float ssrc[NN], sdst[NN], aself[NN];
  float rs[NN], sc[NN];
  float red[16];
  float valk[KTOP];
  int   idxk[KTOP];
  int   row_start[NN+1];
  int   fill[NN];
  unsigned char csr_src[EPG];  // node ids < 48 fit in u8
};

__device__ __forceinline__ float fast_tanh(float x) {
  // post-topk use only: 1 - 2/(e^{2x}+1); saturates correctly at +/-1
  float e = __expf(2.f * x);
  return 1.f - 2.f * __builtin_amdgcn_rcpf(e + 1.f);
}

// R8 proven GEMM: 4-k software-pipelined W prefetch, acc[6][4]/thread.
// 256 threads = 32 cols(x4) x 8 rows(x6); h-reads are LDS broadcasts.
template<int KD>
__device__ __forceinline__ void gemm48(const float* in, const float* __restrict__ W,
                                       int t, float acc[6][4]) {
  const int col = t & 31, row = t >> 5;
  const int c0 = col * 4, n0 = row * 6;
  #pragma unroll
  for (int i = 0; i < 6; ++i)
    #pragma unroll
    for (int j = 0; j < 4; ++j) acc[i][j] = 0.f;
  const float* wp = W + c0;
  float4 w0 = *(const float4*)(wp + 0*HIDC);
  float4 w1 = *(const float4*)(wp + 1*HIDC);
  float4 w2 = *(const float4*)(wp + 2*HIDC);
  float4 w3 = *(const float4*)(wp + 3*HIDC);
  #pragma unroll 2
  for (int kb = 0; kb < KD - 4; kb += 4) {
    const float* np = wp + (size_t)(kb + 4) * HIDC;
    float4 nw0 = *(const float4*)(np + 0*HIDC);
    float4 nw1 = *(const float4*)(np + 1*HIDC);
    float4 nw2 = *(const float4*)(np + 2*HIDC);
    float4 nw3 = *(const float4*)(np + 3*HIDC);
    #pragma unroll
    for (int i = 0; i < 6; ++i) {
      float4 h = *(const float4*)(in + (n0+i)*KD + kb);
      acc[i][0] = fmaf(h.w, w3.x, fmaf(h.z, w2.x, fmaf(h.y, w1.x, fmaf(h.x, w0.x, acc[i][0]))));
      acc[i][1] = fmaf(h.w, w3.y, fmaf(h.z, w2.y, fmaf(h.y, w1.y, fmaf(h.x, w0.y, acc[i][1]))));
      acc[i][2] = fmaf(h.w, w3.z, fmaf(h.z, w2.z, fmaf(h.y, w1.z, fmaf(h.x, w0.z, acc[i][2]))));
      acc[i][3] = fmaf(h.w, w3.w, fmaf(h.z, w2.w, fmaf(h.y, w1.w, fmaf(h.x, w0.w, acc[i][3]))));
    }
    w0 = nw0; w1 = nw1; w2 = nw2; w3 = nw3;
  }
  {
    const int kb = KD - 4;
    #pragma unroll
    for (int i = 0; i < 6; ++i) {
      float4 h = *(const float4*)(in + (n0+i)*KD + kb);
      acc[i][0] = fmaf(h.w, w3.x, fmaf(h.z, w2.x, fmaf(h.y, w1.x, fmaf(h.x, w0.x, acc[i][0]))));
      acc[i][1] = fmaf(h.w, w3.y, fmaf(h.z, w2.y, fmaf(h.y, w1.y, fmaf(h.x, w0.y, acc[i][1]))));
      acc[i][2] = fmaf(h.w, w3.z, fmaf(h.z, w2.z, fmaf(h.y, w1.z, fmaf(h.x, w0.z, acc[i][2]))));
      acc[i][3] = fmaf(h.w, w3.w, fmaf(h.z, w2.w, fmaf(h.y, w1.w, fmaf(h.x, w0.w, acc[i][3]))));
    }
  }
}

template<int KD, bool RELU>
__device__ __forceinline__ void gat_layer(SM& s, const float* in, float* hmid, float* outbuf,
                                          const float* __restrict__ W,
                                          const float* __restrict__ avs,
                                          const float* __restrict__ avd,
                                          const float* __restrict__ bias,
                                          const float* __restrict__ lnw,
                                          const float* __restrict__ lnb, int t) {
  float acc[6][4];
  gemm48<KD>(in, W, t, acc);
  const int col = t & 31, row = t >> 5, c0 = col * 4, n0 = row * 6;
  // store messages + attention-scalar epilogue (free from live accumulators)
  float4 asv = *(const float4*)(avs + c0);
  float4 adv = *(const float4*)(avd + c0);
  #pragma unroll
  for (int i = 0; i < 6; ++i) {
    float4 v = make_float4(acc[i][0], acc[i][1], acc[i][2], acc[i][3]);
    *(float4*)(hmid + (n0+i)*HIDC + c0) = v;
    float ps = v.x*asv.x + v.y*asv.y + v.z*asv.z + v.w*asv.w;
    float pd = v.x*adv.x + v.y*adv.y + v.z*adv.z + v.w*adv.w;
    #pragma unroll
    for (int off = 16; off > 0; off >>= 1) {
      ps += __shfl_xor(ps, off, 32);
      pd += __shfl_xor(pd, off, 32);
    }
    if (col == 0) { s.ssrc[n0+i] = ps; s.sdst[n0+i] = pd; }
  }
  __syncthreads();

  // parallel per-node softmax: 4 lanes per node (t < 192)
  if (t < 4*NN) {
    const int n = t >> 2, l = t & 3;
    const int b0 = s.row_start[n], b1 = s.row_start[n+1];
    const float di = s.sdst[n];
    float es = s.ssrc[n] + di; es = es > 0.f ? es : 0.2f*es;  // self loop
    float m = es;
    for (int q = b0 + l; q < b1; q += 4) {
      float e = s.ssrc[s.csr_src[q]] + di; e = e > 0.f ? e : 0.2f*e;
      s.alpha[q] = e;
      m = fmaxf(m, e);
    }
    m = fmaxf(m, __shfl_xor(m, 1, 4));
    m = fmaxf(m, __shfl_xor(m, 2, 4));
    float pself = expf(es - m);
    float z = (l == 0) ? pself : 0.f;
    for (int q = b0 + l; q < b1; q += 4) {
      float p = expf(s.alpha[q] - m); s.alpha[q] = p; z += p;
    }
    z += __shfl_xor(z, 1, 4);
    z += __shfl_xor(z, 2, 4);
    float inv = 1.f / (z + 1e-16f);
    for (int q = b0 + l; q < b1; q += 4) s.alpha[q] *= inv;
    if (l == 0) s.aself[n] = pself * inv;
  }
  __syncthreads();

  // aggregation (+ bias): 6 rows interleaved (6 independent LDS chains),
  // (alpha,csr) prefetched one step ahead; fused LN statistics.
  // Isolated from R12 (the GEMM deep-pipeline that regressed is NOT included).
  {
    const int cg = t & 31, rg = t >> 5;
    const float4 bc = *(const float4*)(bias + cg*4);
    const float4* hm4 = (const float4*)hmid;
    float4* ob4 = (float4*)outbuf;
    float4 av[6];
    int qq[6], ee[6];
    int maxc = 0;
    #pragma unroll
    for (int j = 0; j < 6; ++j) {
      const int i = rg + 8*j;
      qq[j] = s.row_start[i]; ee[j] = s.row_start[i+1];
      int c = ee[j] - qq[j]; maxc = c > maxc ? c : maxc;
      float4 hv = hm4[i*32 + cg];
      const float asf = s.aself[i];
      av[j] = make_float4(asf*hv.x, asf*hv.y, asf*hv.z, asf*hv.w);
    }
    float a_c[6]; int s_c[6];
    #pragma unroll
    for (int j = 0; j < 6; ++j) {
      a_c[j] = 0.f; s_c[j] = 0;
      if (qq[j] < ee[j]) { a_c[j] = s.alpha[qq[j]]; s_c[j] = s.csr_src[qq[j]]; }
    }
    for (int it = 0; it < maxc; ++it) {
      float a_n[6]; int s_n[6];
      #pragma unroll
      for (int j = 0; j < 6; ++j) {
        a_n[j] = 0.f; s_n[j] = 0;
        const int qn = qq[j] + it + 1;
        if (qn < ee[j]) { a_n[j] = s.alpha[qn]; s_n[j] = s.csr_src[qn]; }
      }
      #pragma unroll
      for (int j = 0; j < 6; ++j) {
        if (qq[j] + it < ee[j]) {
          float4 h4 = hm4[s_c[j]*32 + cg];
          av[j].x = fmaf(a_c[j], h4.x, av[j].x);
          av[j].y = fmaf(a_c[j], h4.y, av[j].y);
          av[j].z = fmaf(a_c[j], h4.z, av[j].z);
          av[j].w = fmaf(a_c[j], h4.w, av[j].w);
        }
      }
      #pragma unroll
      for (int j = 0; j < 6; ++j) { a_c[j] = a_n[j]; s_c[j] = s_n[j]; }
    }
    float lsum = 0.f, lsq = 0.f;
    #pragma unroll
    for (int j = 0; j < 6; ++j) {
      const int i = rg + 8*j;
      av[j].x += bc.x; av[j].y += bc.y; av[j].z += bc.z; av[j].w += bc.w;
      ob4[i*32 + cg] = av[j];
      lsum += av[j].x + av[j].y + av[j].z + av[j].w;
      lsq = fmaf(av[j].x, av[j].x, lsq); lsq = fmaf(av[j].y, av[j].y, lsq);
      lsq = fmaf(av[j].z, av[j].z, lsq); lsq = fmaf(av[j].w, av[j].w, lsq);
    }
    #pragma unroll
    for (int off = 32; off > 0; off >>= 1) {
      lsum += __shfl_xor(lsum, off, 64);
      lsq  += __shfl_xor(lsq,  off, 64);
    }
    const int wid = t >> 6;
    if ((t & 63) == 0) { s.red[wid] = lsum; s.red[8+wid] = lsq; }
  }
  __syncthreads();

  // LN apply, float4; every thread computes mu/rstd redundantly
  {
    float su = s.red[0] + s.red[1] + s.red[2] + s.red[3];
    float sq = s.red[8] + s.red[9] + s.red[10] + s.red[11];
    const float inv_n = 1.f / (NN*HIDC);
    const float mu = su * inv_n;
    const float rstd = 1.f / sqrtf(sq * inv_n - mu*mu + 1e-5f);
    const int cg = t & 31;
    const float4 wc  = *(const float4*)(lnw + cg*4);
    const float4 bcn = *(const float4*)(lnb + cg*4);
    float4* ob4 = (float4*)outbuf;
    for (int e = t; e < NN*32; e += NTH) {
      float4 v = ob4[e];
      v.x = (v.x - mu)*rstd*wc.x + bcn.x;
      v.y = (v.y - mu)*rstd*wc.y + bcn.y;
      v.z = (v.z - mu)*rstd*wc.z + bcn.z;
      v.w = (v.w - mu)*rstd*wc.w + bcn.w;
      if (RELU) {
        v.x = fmaxf(v.x, 0.f); v.y = fmaxf(v.y, 0.f);
        v.z = fmaxf(v.z, 0.f); v.w = fmaxf(v.w, 0.f);
      }
      ob4[e] = v;
    }
  }
  __syncthreads();
}

__global__ __launch_bounds__(NTH)
void gat_fused(const float* __restrict__ x,
               const int* __restrict__ edge_src, const int* __restrict__ edge_dst,
               const float* __restrict__ W1, const float* __restrict__ as1, const float* __restrict__ ad1, const float* __restrict__ b1,
               const float* __restrict__ W2, const float* __restrict__ as2, const float* __restrict__ ad2, const float* __restrict__ b2,
               const float* __restrict__ W3, const float* __restrict__ as3, const float* __restrict__ ad3, const float* __restrict__ b3,
               const float* __restrict__ ln1w, const float* __restrict__ ln1b,
               const float* __restrict__ ln2w, const float* __restrict__ ln2b,
               const float* __restrict__ ln3w, const float* __restrict__ ln3b,
               const float* __restrict__ poolw,
               const float* __restrict__ fc1w, const float* __restrict__ fc1b,
               const float* __restrict__ fc2w, const float* __restrict__ fc2b,
               float* __restrict__ out) {
  __shared__ SM s;
  const int g = blockIdx.x, t = threadIdx.x;
  const int base = g * NN;

  // stage x [48][64] into hA (vectorized)
  {
    const float4* xs = (const float4*)(x + (size_t)base*FIN);
    for (int e = t; e < NN*FIN/4; e += NTH) ((float4*)s.hA)[e] = xs[e];
  }

  // build per-graph CSR (incoming lists) in LDS
  if (t < NN) s.fill[t] = 0;
  __syncthreads();
  for (int e = t; e < EPG; e += NTH)
    atomicAdd(&s.fill[edge_dst[(size_t)g*EPG + e] - base], 1);
  __syncthreads();
  if (t < 64) {  // wave-0 shuffle prefix scan
    int cnt = (t < NN) ? s.fill[t] : 0;
    int xv = cnt;
    #pragma unroll
    for (int d = 1; d < 64; d <<= 1) {
      int v = __shfl_up(xv, d, 64);
      if (t >= d) xv += v;
    }
    if (t < NN) { s.row_start[t] = xv - cnt; s.fill[t] = xv - cnt; }
    if (t == NN-1) s.row_start[NN] = xv;
  }
  __syncthreads();
  for (int e = t; e < EPG; e += NTH) {
    int d  = edge_dst[(size_t)g*EPG + e] - base;
    int sl = edge_src[(size_t)g*EPG + e] - base;
    int pos = atomicAdd(&s.fill[d], 1);
    s.csr_src[pos] = (unsigned char)sl;
  }
  __syncthreads();

  gat_layer<FIN,  true >(s, s.hA, s.hB, s.hA, W1, as1, ad1, b1, ln1w, ln1b, t);
  gat_layer<HIDC, true >(s, s.hA, s.hB, s.hA, W2, as2, ad2, b2, ln2w, ln2b, t);
  gat_layer<HIDC, false>(s, s.hA, s.hB, s.hA, W3, as3, ad3, b3, ln3w, ln3b, t);

  // 1/||pool_w|| — per-wave shuffle, no LDS, no barrier
  float invnorm;
  {
    const int ln = t & 63;
    float p0 = poolw[ln], p1 = poolw[ln + 64];
    float v = p0*p0 + p1*p1;
    #pragma unroll
    for (int off = 32; off > 0; off >>= 1) v += __shfl_xor(v, off, 64);
    invnorm = 1.f / sqrtf(v);
  }

  // scores tanh(h.w/||w||) and row sums of h  (precise tanhf: top-k values)
  {
    const int col = t & 31, row = t >> 5, n0 = row * 6;
    float pwv[4];
    #pragma unroll
    for (int q = 0; q < 4; ++q) pwv[q] = poolw[col + 32*q];
    #pragma unroll
    for (int i = 0; i < 6; ++i) {
      float d = 0.f, r = 0.f;
      #pragma unroll
      for (int q = 0; q < 4; ++q) {
        float v = s.hA[(n0+i)*HIDC + col + 32*q];
        d = fmaf(v, pwv[q], d); r += v;
      }
      #pragma unroll
      for (int off = 16; off > 0; off >>= 1) {
        d += __shfl_xor(d, off, 32);
        r += __shfl_xor(r, off, 32);
      }
      if (col == 0) { s.sc[n0+i] = tanhf(d * invnorm); s.rs[n0+i] = r; }
    }
  }
  __syncthreads();

  // top-4 via wave-0 shuffle argmax (strict >, lowest index on tie — lax.top_k order)
  if (t < 64) {
    float cur = (t < NN) ? s.sc[t] : -1e30f;
    #pragma unroll
    for (int k = 0; k < KTOP; ++k) {
      float bv = cur; int bi = t;
      #pragma unroll
      for (int d = 1; d < 64; d <<= 1) {
        float ov = __shfl_xor(bv, d, 64);
        int   oi = __shfl_xor(bi, d, 64);
        if (ov > bv || (ov == bv && oi < bi)) { bv = ov; bi = oi; }
      }
      if (t == 0) { s.valk[k] = bv; s.idxk[k] = bi; }
      if (t == bi) cur = -1e30f;
    }
  }
  __syncthreads();

  float* og = out + (size_t)g * OUTW;
  for (int o = t; o < KTOP*HIDC; o += NTH) {
    int k = o >> 7, c = o & 127;
    og[o] = s.hA[s.idxk[k]*HIDC + c] * s.valk[k];
  }

  // t = tanh(h @ fc1 + fc1_b) kept in REGISTERS; fc2 logits computed directly
  // from the accumulators (no hB round-trip, no extra barrier).
  {
    float acc[6][4];
    gemm48<HIDC>(s.hA, fc1w, t, acc);
    const int col = t & 31, row = t >> 5, c0 = col*4, n0 = row*6;
    float4 bv = *(const float4*)(fc1b + c0);
    #pragma unroll
    for (int i = 0; i < 6; ++i) {
      acc[i][0] = fast_tanh(acc[i][0] + bv.x);
      acc[i][1] = fast_tanh(acc[i][1] + bv.y);
      acc[i][2] = fast_tanh(acc[i][2] + bv.z);
      acc[i][3] = fast_tanh(acc[i][3] + bv.w);
    }
    // fc2 weights for our 4 columns: fc2w[(c0+j)*NATT + a]
    float f2[4][NATT];
    #pragma unroll
    for (int j = 0; j < 4; ++j) {
      float4 lo = *(const float4*)(fc2w + (size_t)(c0+j)*NATT);
      float4 hi = *(const float4*)(fc2w + (size_t)(c0+j)*NATT + 4);
      f2[j][0] = lo.x; f2[j][1] = lo.y; f2[j][2] = lo.z; f2[j][3] = lo.w;
      f2[j][4] = hi.x; f2[j][5] = hi.y; f2[j][6] = hi.z; f2[j][7] = hi.w;
    }
    #pragma unroll
    for (int i = 0; i < 6; ++i) {
      float lg[NATT];
      #pragma unroll
      for (int a = 0; a < NATT; ++a) {
        lg[a] = acc[i][0]*f2[0][a] + acc[i][1]*f2[1][a]
              + acc[i][2]*f2[2][a] + acc[i][3]*f2[3][a];
      }
      #pragma unroll
      for (int a = 0; a < NATT; ++a) {
        #pragma unroll
        for (int off = 16; off > 0; off >>= 1) lg[a] += __shfl_xor(lg[a], off, 32);
      }
      if (col == 0) {
        #pragma unroll
        for (int a = 0; a < NATT; ++a) s.alpha[(n0+i)*NATT + a] = lg[a] + fc2b[a];
      }
    }
  }
  __syncthreads();

  // head softmax over nodes, wave-parallel: wave w handles heads w and w+4
  {
    const int wv = t >> 6, ln = t & 63;
    #pragma unroll
    for (int aa = 0; aa < 2; ++aa) {
      const int a = wv + 4*aa;
      float lg = (ln < NN) ? s.alpha[ln*NATT + a] : -1e30f;
      float m = lg;
      #pragma unroll
      for (int off = 32; off > 0; off >>= 1) m = fmaxf(m, __shfl_xor(m, off, 64));
      float p = (ln < NN) ? expf(lg - m) : 0.f;
      float w_n = (ln < NN) ? s.rs[ln] : 0.f;
      float zz = p, acc0 = p * w_n;
      #pragma unroll
      for (int off = 32; off > 0; off >>= 1) {
        zz   += __shfl_xor(zz,   off, 64);
        acc0 += __shfl_xor(acc0, off, 64);
      }
      if (ln == 0) og[KTOP*HIDC + a] = acc0 / zz * (1.0f / NATT);
    }
  }
}

extern "C" void kernel_launch(void* const* d_in, const int* in_sizes, int n_in,
                              void* d_out, int out_size, void* d_ws, size_t ws_size,
                              hipStream_t stream) {
  (void)in_sizes; (void)n_in; (void)d_ws; (void)ws_size; (void)out_size;
  const float* x    = (const float*)d_in[0];
  const int*   esrc = (const int*)  d_in[1];
  const int*   edst = (const int*)  d_in[2];
  // d_in[3] = batch (implicit in layout, unused)
  const float* W1   = (const float*)d_in[4];
  const float* as1  = (const float*)d_in[5];
  const float* ad1  = (const float*)d_in[6];
  const float* b1   = (const float*)d_in[7];
  const float* W2   = (const float*)d_in[8];
  const float* as2  = (const float*)d_in[9];
  const float* ad2  = (const float*)d_in[10];
  const float* b2   = (const float*)d_in[11];
  const float* W3   = (const float*)d_in[12];
  const float* as3  = (const float*)d_in[13];
  const float* ad3  = (const float*)d_in[14];
  const float* b3   = (const float*)d_in[15];
  const float* ln1w = (const float*)d_in[16];
  const float* ln1b = (const float*)d_in[17];
  const float* ln2w = (const float*)d_in[18];
  const float* ln2b = (const float*)d_in[19];
  const float* ln3w = (const float*)d_in[20];
  const float* ln3b = (const float*)d_in[21];
  const float* pw   = (const float*)d_in[22];
  const float* fc1w = (const float*)d_in[23];
  const float* fc1b = (const float*)d_in[24];
  const float* fc2w = (const float*)d_in[25];
  const float* fc2b = (const float*)d_in[26];
  float* out = (float*)d_out;

  gat_fused<<<NG, NTH, 0, stream>>>(x, esrc, edst,
                                    W1, as1, ad1, b1,
                                    W2, as2, ad2, b2,
                                    W3, as3, ad3, b3,
                                    ln1w, ln1b, ln2w, ln2b, ln3w, ln3b,
                                    pw, fc1w, fc1b, fc2w, fc2b, out);
}

// Round 18
// 244.064 us; speedup vs baseline: 1.0788x; 1.0788x over previous
//
#include <hip/hip_runtime.h>
#include <math.h>

#define NG   2048
#define NN   48
#define FIN  64
#define HIDC 128
#define DEG  8
#define EPG  (NN*DEG)   // 384 edges per graph
#define NATT 8
#define KTOP 4
#define NTH  256
#define OUTW (KTOP*HIDC + NATT)  // 520

struct alignas(16) SM {
  float hA[NN*HIDC];        // 24KB
  float hB[NN*HIDC];        // 24KB message buffer (layers only)
  float alpha[EPG];         // per-edge alpha; reused as attn logits (48*8)
  float ssrc[NN], sdst[NN], aself[NN];
  float rs[NN], sc[NN];
  float red[16];
  float valk[KTOP];
  int   idxk[KTOP];
  int   row_start[NN+1];
  int   fill[NN];
  unsigned char csr_src[EPG];  // node ids < 48 fit in u8
};

__device__ __forceinline__ float fast_tanh(float x) {
  // post-topk use only: 1 - 2/(e^{2x}+1); saturates correctly at +/-1
  float e = __expf(2.f * x);
  return 1.f - 2.f * __builtin_amdgcn_rcpf(e + 1.f);
}

// R8 proven GEMM: 4-k software-pipelined W prefetch, acc[6][4]/thread.
// 256 threads = 32 cols(x4) x 8 rows(x6); h-reads are LDS broadcasts.
template<int KD>
__device__ __forceinline__ void gemm48(const float* in, const float* __restrict__ W,
                                       int t, float acc[6][4]) {
  const int col = t & 31, row = t >> 5;
  const int c0 = col * 4, n0 = row * 6;
  #pragma unroll
  for (int i = 0; i < 6; ++i)
    #pragma unroll
    for (int j = 0; j < 4; ++j) acc[i][j] = 0.f;
  const float* wp = W + c0;
  float4 w0 = *(const float4*)(wp + 0*HIDC);
  float4 w1 = *(const float4*)(wp + 1*HIDC);
  float4 w2 = *(const float4*)(wp + 2*HIDC);
  float4 w3 = *(const float4*)(wp + 3*HIDC);
  #pragma unroll 2
  for (int kb = 0; kb < KD - 4; kb += 4) {
    const float* np = wp + (size_t)(kb + 4) * HIDC;
    float4 nw0 = *(const float4*)(np + 0*HIDC);
    float4 nw1 = *(const float4*)(np + 1*HIDC);
    float4 nw2 = *(const float4*)(np + 2*HIDC);
    float4 nw3 = *(const float4*)(np + 3*HIDC);
    #pragma unroll
    for (int i = 0; i < 6; ++i) {
      float4 h = *(const float4*)(in + (n0+i)*KD + kb);
      acc[i][0] = fmaf(h.w, w3.x, fmaf(h.z, w2.x, fmaf(h.y, w1.x, fmaf(h.x, w0.x, acc[i][0]))));
      acc[i][1] = fmaf(h.w, w3.y, fmaf(h.z, w2.y, fmaf(h.y, w1.y, fmaf(h.x, w0.y, acc[i][1]))));
      acc[i][2] = fmaf(h.w, w3.z, fmaf(h.z, w2.z, fmaf(h.y, w1.z, fmaf(h.x, w0.z, acc[i][2]))));
      acc[i][3] = fmaf(h.w, w3.w, fmaf(h.z, w2.w, fmaf(h.y, w1.w, fmaf(h.x, w0.w, acc[i][3]))));
    }
    w0 = nw0; w1 = nw1; w2 = nw2; w3 = nw3;
  }
  {
    const int kb = KD - 4;
    #pragma unroll
    for (int i = 0; i < 6; ++i) {
      float4 h = *(const float4*)(in + (n0+i)*KD + kb);
      acc[i][0] = fmaf(h.w, w3.x, fmaf(h.z, w2.x, fmaf(h.y, w1.x, fmaf(h.x, w0.x, acc[i][0]))));
      acc[i][1] = fmaf(h.w, w3.y, fmaf(h.z, w2.y, fmaf(h.y, w1.y, fmaf(h.x, w0.y, acc[i][1]))));
      acc[i][2] = fmaf(h.w, w3.z, fmaf(h.z, w2.z, fmaf(h.y, w1.z, fmaf(h.x, w0.z, acc[i][2]))));
      acc[i][3] = fmaf(h.w, w3.w, fmaf(h.z, w2.w, fmaf(h.y, w1.w, fmaf(h.x, w0.w, acc[i][3]))));
    }
  }
}

template<int KD, bool RELU>
__device__ __forceinline__ void gat_layer(SM& s, const float* in, float* hmid, float* outbuf,
                                          const float* __restrict__ W,
                                          const float* __restrict__ avs,
                                          const float* __restrict__ avd,
                                          const float* __restrict__ bias,
                                          const float* __restrict__ lnw,
                                          const float* __restrict__ lnb, int t) {
  float acc[6][4];
  gemm48<KD>(in, W, t, acc);
  const int col = t & 31, row = t >> 5, c0 = col * 4, n0 = row * 6;
  // store messages + attention-scalar epilogue (free from live accumulators)
  float4 asv = *(const float4*)(avs + c0);
  float4 adv = *(const float4*)(avd + c0);
  #pragma unroll
  for (int i = 0; i < 6; ++i) {
    float4 v = make_float4(acc[i][0], acc[i][1], acc[i][2], acc[i][3]);
    *(float4*)(hmid + (n0+i)*HIDC + c0) = v;
    float ps = v.x*asv.x + v.y*asv.y + v.z*asv.z + v.w*asv.w;
    float pd = v.x*adv.x + v.y*adv.y + v.z*adv.z + v.w*adv.w;
    #pragma unroll
    for (int off = 16; off > 0; off >>= 1) {
      ps += __shfl_xor(ps, off, 32);
      pd += __shfl_xor(pd, off, 32);
    }
    if (col == 0) { s.ssrc[n0+i] = ps; s.sdst[n0+i] = pd; }
  }
  __syncthreads();

  // parallel per-node softmax: 4 lanes per node (t < 192)
  if (t < 4*NN) {
    const int n = t >> 2, l = t & 3;
    const int b0 = s.row_start[n], b1 = s.row_start[n+1];
    const float di = s.sdst[n];
    float es = s.ssrc[n] + di; es = es > 0.f ? es : 0.2f*es;  // self loop
    float m = es;
    for (int q = b0 + l; q < b1; q += 4) {
      float e = s.ssrc[s.csr_src[q]] + di; e = e > 0.f ? e : 0.2f*e;
      s.alpha[q] = e;
      m = fmaxf(m, e);
    }
    m = fmaxf(m, __shfl_xor(m, 1, 4));
    m = fmaxf(m, __shfl_xor(m, 2, 4));
    float pself = expf(es - m);
    float z = (l == 0) ? pself : 0.f;
    for (int q = b0 + l; q < b1; q += 4) {
      float p = expf(s.alpha[q] - m); s.alpha[q] = p; z += p;
    }
    z += __shfl_xor(z, 1, 4);
    z += __shfl_xor(z, 2, 4);
    float inv = 1.f / (z + 1e-16f);
    for (int q = b0 + l; q < b1; q += 4) s.alpha[q] *= inv;
    if (l == 0) s.aself[n] = pself * inv;
  }
  __syncthreads();

  // aggregation (+ bias), float4 over columns, fused LN statistics.
  {
    const int cg = t & 31, rg = t >> 5;
    const float4 bc = *(const float4*)(bias + cg*4);
    const float4* hm4 = (const float4*)hmid;
    float4* ob4 = (float4*)outbuf;
    float lsum = 0.f, lsq = 0.f;
    #pragma unroll
    for (int j = 0; j < 6; ++j) {
      const int i = rg + 8*j;
      const int b0 = s.row_start[i], b1 = s.row_start[i+1];
      float4 hv = hm4[i*32 + cg];
      const float asf = s.aself[i];
      float4 av = make_float4(asf*hv.x, asf*hv.y, asf*hv.z, asf*hv.w);
      int q = b0;
      float a_nxt = 0.f; int s_nxt = 0;
      if (q < b1) { a_nxt = s.alpha[q]; s_nxt = s.csr_src[q]; }
      while (q < b1) {
        const float a = a_nxt; const int sc = s_nxt;
        ++q;
        if (q < b1) { a_nxt = s.alpha[q]; s_nxt = s.csr_src[q]; }
        float4 h4 = hm4[sc*32 + cg];
        av.x = fmaf(a, h4.x, av.x);
        av.y = fmaf(a, h4.y, av.y);
        av.z = fmaf(a, h4.z, av.z);
        av.w = fmaf(a, h4.w, av.w);
      }
      av.x += bc.x; av.y += bc.y; av.z += bc.z; av.w += bc.w;
      ob4[i*32 + cg] = av;
      lsum += av.x + av.y + av.z + av.w;
      lsq = fmaf(av.x, av.x, lsq); lsq = fmaf(av.y, av.y, lsq);
      lsq = fmaf(av.z, av.z, lsq); lsq = fmaf(av.w, av.w, lsq);
    }
    #pragma unroll
    for (int off = 32; off > 0; off >>= 1) {
      lsum += __shfl_xor(lsum, off, 64);
      lsq  += __shfl_xor(lsq,  off, 64);
    }
    const int wid = t >> 6;
    if ((t & 63) == 0) { s.red[wid] = lsum; s.red[8+wid] = lsq; }
  }
  __syncthreads();

  // LN apply, float4; every thread computes mu/rstd redundantly
  {
    float su = s.red[0] + s.red[1] + s.red[2] + s.red[3];
    float sq = s.red[8] + s.red[9] + s.red[10] + s.red[11];
    const float inv_n = 1.f / (NN*HIDC);
    const float mu = su * inv_n;
    const float rstd = 1.f / sqrtf(sq * inv_n - mu*mu + 1e-5f);
    const int cg = t & 31;
    const float4 wc  = *(const float4*)(lnw + cg*4);
    const float4 bcn = *(const float4*)(lnb + cg*4);
    float4* ob4 = (float4*)outbuf;
    for (int e = t; e < NN*32; e += NTH) {
      float4 v = ob4[e];
      v.x = (v.x - mu)*rstd*wc.x + bcn.x;
      v.y = (v.y - mu)*rstd*wc.y + bcn.y;
      v.z = (v.z - mu)*rstd*wc.z + bcn.z;
      v.w = (v.w - mu)*rstd*wc.w + bcn.w;
      if (RELU) {
        v.x = fmaxf(v.x, 0.f); v.y = fmaxf(v.y, 0.f);
        v.z = fmaxf(v.z, 0.f); v.w = fmaxf(v.w, 0.f);
      }
      ob4[e] = v;
    }
  }
  __syncthreads();
}

__global__ __launch_bounds__(NTH)
void gat_fused(const float* __restrict__ x,
               const int* __restrict__ edge_src, const int* __restrict__ edge_dst,
               const float* __restrict__ W1, const float* __restrict__ as1, const float* __restrict__ ad1, const float* __restrict__ b1,
               const float* __restrict__ W2, const float* __restrict__ as2, const float* __restrict__ ad2, const float* __restrict__ b2,
               const float* __restrict__ W3, const float* __restrict__ as3, const float* __restrict__ ad3, const float* __restrict__ b3,
               const float* __restrict__ ln1w, const float* __restrict__ ln1b,
               const float* __restrict__ ln2w, const float* __restrict__ ln2b,
               const float* __restrict__ ln3w, const float* __restrict__ ln3b,
               const float* __restrict__ poolw,
               const float* __restrict__ fc1w, const float* __restrict__ fc1b,
               const float* __restrict__ fc2w, const float* __restrict__ fc2b,
               float* __restrict__ out) {
  __shared__ SM s;
  const int g = blockIdx.x, t = threadIdx.x;
  const int base = g * NN;

  // stage x [48][64] into hA (vectorized)
  {
    const float4* xs = (const float4*)(x + (size_t)base*FIN);
    for (int e = t; e < NN*FIN/4; e += NTH) ((float4*)s.hA)[e] = xs[e];
  }

  // build per-graph CSR (incoming lists) in LDS
  if (t < NN) s.fill[t] = 0;
  __syncthreads();
  for (int e = t; e < EPG; e += NTH)
    atomicAdd(&s.fill[edge_dst[(size_t)g*EPG + e] - base], 1);
  __syncthreads();
  if (t < 64) {  // wave-0 shuffle prefix scan
    int cnt = (t < NN) ? s.fill[t] : 0;
    int xv = cnt;
    #pragma unroll
    for (int d = 1; d < 64; d <<= 1) {
      int v = __shfl_up(xv, d, 64);
      if (t >= d) xv += v;
    }
    if (t < NN) { s.row_start[t] = xv - cnt; s.fill[t] = xv - cnt; }
    if (t == NN-1) s.row_start[NN] = xv;
  }
  __syncthreads();
  for (int e = t; e < EPG; e += NTH) {
    int d  = edge_dst[(size_t)g*EPG + e] - base;
    int sl = edge_src[(size_t)g*EPG + e] - base;
    int pos = atomicAdd(&s.fill[d], 1);
    s.csr_src[pos] = (unsigned char)sl;
  }
  __syncthreads();

  gat_layer<FIN,  true >(s, s.hA, s.hB, s.hA, W1, as1, ad1, b1, ln1w, ln1b, t);
  gat_layer<HIDC, true >(s, s.hA, s.hB, s.hA, W2, as2, ad2, b2, ln2w, ln2b, t);
  gat_layer<HIDC, false>(s, s.hA, s.hB, s.hA, W3, as3, ad3, b3, ln3w, ln3b, t);

  // 1/||pool_w|| — per-wave shuffle, no LDS, no barrier
  float invnorm;
  {
    const int ln = t & 63;
    float p0 = poolw[ln], p1 = poolw[ln + 64];
    float v = p0*p0 + p1*p1;
    #pragma unroll
    for (int off = 32; off > 0; off >>= 1) v += __shfl_xor(v, off, 64);
    invnorm = 1.f / sqrtf(v);
  }

  // scores tanh(h.w/||w||) and row sums of h  (precise tanhf: top-k values)
  {
    const int col = t & 31, row = t >> 5, n0 = row * 6;
    float pwv[4];
    #pragma unroll
    for (int q = 0; q < 4; ++q) pwv[q] = poolw[col + 32*q];
    #pragma unroll
    for (int i = 0; i < 6; ++i) {
      float d = 0.f, r = 0.f;
      #pragma unroll
      for (int q = 0; q < 4; ++q) {
        float v = s.hA[(n0+i)*HIDC + col + 32*q];
        d = fmaf(v, pwv[q], d); r += v;
      }
      #pragma unroll
      for (int off = 16; off > 0; off >>= 1) {
        d += __shfl_xor(d, off, 32);
        r += __shfl_xor(r, off, 32);
      }
      if (col == 0) { s.sc[n0+i] = tanhf(d * invnorm); s.rs[n0+i] = r; }
    }
  }
  __syncthreads();

  // top-4 via wave-0 shuffle argmax (strict >, lowest index on tie — lax.top_k order)
  if (t < 64) {
    float cur = (t < NN) ? s.sc[t] : -1e30f;
    #pragma unroll
    for (int k = 0; k < KTOP; ++k) {
      float bv = cur; int bi = t;
      #pragma unroll
      for (int d = 1; d < 64; d <<= 1) {
        float ov = __shfl_xor(bv, d, 64);
        int   oi = __shfl_xor(bi, d, 64);
        if (ov > bv || (ov == bv && oi < bi)) { bv = ov; bi = oi; }
      }
      if (t == 0) { s.valk[k] = bv; s.idxk[k] = bi; }
      if (t == bi) cur = -1e30f;
    }
  }
  __syncthreads();

  float* og = out + (size_t)g * OUTW;
  for (int o = t; o < KTOP*HIDC; o += NTH) {
    int k = o >> 7, c = o & 127;
    og[o] = s.hA[s.idxk[k]*HIDC + c] * s.valk[k];
  }

  // t = tanh(h @ fc1 + fc1_b) kept in REGISTERS; fc2 logits computed directly
  // from the accumulators (no hB round-trip, no extra barrier).
  {
    float acc[6][4];
    gemm48<HIDC>(s.hA, fc1w, t, acc);
    const int col = t & 31, row = t >> 5, c0 = col*4, n0 = row*6;
    float4 bv = *(const float4*)(fc1b + c0);
    #pragma unroll
    for (int i = 0; i < 6; ++i) {
      acc[i][0] = fast_tanh(acc[i][0] + bv.x);
      acc[i][1] = fast_tanh(acc[i][1] + bv.y);
      acc[i][2] = fast_tanh(acc[i][2] + bv.z);
      acc[i][3] = fast_tanh(acc[i][3] + bv.w);
    }
    // fc2 weights for our 4 columns: fc2w[(c0+j)*NATT + a]
    float f2[4][NATT];
    #pragma unroll
    for (int j = 0; j < 4; ++j) {
      float4 lo = *(const float4*)(fc2w + (size_t)(c0+j)*NATT);
      float4 hi = *(const float4*)(fc2w + (size_t)(c0+j)*NATT + 4);
      f2[j][0] = lo.x; f2[j][1] = lo.y; f2[j][2] = lo.z; f2[j][3] = lo.w;
      f2[j][4] = hi.x; f2[j][5] = hi.y; f2[j][6] = hi.z; f2[j][7] = hi.w;
    }
    #pragma unroll
    for (int i = 0; i < 6; ++i) {
      float lg[NATT];
      #pragma unroll
      for (int a = 0; a < NATT; ++a) {
        lg[a] = acc[i][0]*f2[0][a] + acc[i][1]*f2[1][a]
              + acc[i][2]*f2[2][a] + acc[i][3]*f2[3][a];
      }
      #pragma unroll
      for (int a = 0; a < NATT; ++a) {
        #pragma unroll
        for (int off = 16; off > 0; off >>= 1) lg[a] += __shfl_xor(lg[a], off, 32);
      }
      if (col == 0) {
        #pragma unroll
        for (int a = 0; a < NATT; ++a) s.alpha[(n0+i)*NATT + a] = lg[a] + fc2b[a];
      }
    }
  }
  __syncthreads();

  // head softmax over nodes, wave-parallel: wave w handles heads w and w+4
  {
    const int wv = t >> 6, ln = t & 63;
    #pragma unroll
    for (int aa = 0; aa < 2; ++aa) {
      const int a = wv + 4*aa;
      float lg = (ln < NN) ? s.alpha[ln*NATT + a] : -1e30f;
      float m = lg;
      #pragma unroll
      for (int off = 32; off > 0; off >>= 1) m = fmaxf(m, __shfl_xor(m, off, 64));
      float p = (ln < NN) ? expf(lg - m) : 0.f;
      float w_n = (ln < NN) ? s.rs[ln] : 0.f;
      float zz = p, acc0 = p * w_n;
      #pragma unroll
      for (int off = 32; off > 0; off >>= 1) {
        zz   += __shfl_xor(zz,   off, 64);
        acc0 += __shfl_xor(acc0, off, 64);
      }
      if (ln == 0) og[KTOP*HIDC + a] = acc0 / zz * (1.0f / NATT);
    }
  }
}

extern "C" void kernel_launch(void* const* d_in, const int* in_sizes, int n_in,
                              void* d_out, int out_size, void* d_ws, size_t ws_size,
                              hipStream_t stream) {
  (void)in_sizes; (void)n_in; (void)d_ws; (void)ws_size; (void)out_size;
  const float* x    = (const float*)d_in[0];
  const int*   esrc = (const int*)  d_in[1];
  const int*   edst = (const int*)  d_in[2];
  // d_in[3] = batch (implicit in layout, unused)
  const float* W1   = (const float*)d_in[4];
  const float* as1  = (const float*)d_in[5];
  const float* ad1  = (const float*)d_in[6];
  const float* b1   = (const float*)d_in[7];
  const float* W2   = (const float*)d_in[8];
  const float* as2  = (const float*)d_in[9];
  const float* ad2  = (const float*)d_in[10];
  const float* b2   = (const float*)d_in[11];
  const float* W3   = (const float*)d_in[12];
  const float* as3  = (const float*)d_in[13];
  const float* ad3  = (const float*)d_in[14];
  const float* b3   = (const float*)d_in[15];
  const float* ln1w = (const float*)d_in[16];
  const float* ln1b = (const float*)d_in[17];
  const float* ln2w = (const float*)d_in[18];
  const float* ln2b = (const float*)d_in[19];
  const float* ln3w = (const float*)d_in[20];
  const float* ln3b = (const float*)d_in[21];
  const float* pw   = (const float*)d_in[22];
  const float* fc1w = (const float*)d_in[23];
  const float* fc1b = (const float*)d_in[24];
  const float* fc2w = (const float*)d_in[25];
  const float* fc2b = (const float*)d_in[26];
  float* out = (float*)d_out;

  gat_fused<<<NG, NTH, 0, stream>>>(x, esrc, edst,
                                    W1, as1, ad1, b1,
                                    W2, as2, ad2, b2,
                                    W3, as3, ad3, b3,
                                    ln1w, ln1b, ln2w, ln2b, ln3w, ln3b,
                                    pw, fc1w, fc1b, fc2w, fc2b, out);
}